// Round 13
// baseline (108.103 us; speedup 1.0000x reference)
//
#include <hip/hip_runtime.h>
#include <stdint.h>

typedef __attribute__((ext_vector_type(8))) short bf16x8;
typedef __attribute__((ext_vector_type(4))) float f32x4;
typedef __attribute__((ext_vector_type(16))) float f32x16;
typedef __attribute__((ext_vector_type(4))) unsigned short us4;
typedef __attribute__((ext_vector_type(4))) unsigned int u32x4;

#define AS1 __attribute__((address_space(1)))
#define AS3 __attribute__((address_space(3)))

static constexpr int Lq = 2048;   // sequence length
static constexpr int Dm = 1024;   // model dim = H*Dh
static constexpr int NH = 16;     // heads
static constexpr int DH = 64;     // head dim

__device__ __forceinline__ unsigned short f2bf(float x) {
  union { float f; uint32_t u; } v; v.f = x;
  uint32_t r = v.u + 0x7FFFu + ((v.u >> 16) & 1u);  // round-to-nearest-even
  return (unsigned short)(r >> 16);
}

#if __has_builtin(__builtin_amdgcn_exp2f)
__device__ __forceinline__ float exp2_fast(float x) { return __builtin_amdgcn_exp2f(x); }
#else
__device__ __forceinline__ float exp2_fast(float x) {
  float r; asm volatile("v_exp_f32 %0, %1" : "=v"(r) : "v"(x)); return r;
}
#endif

__device__ __forceinline__ uint32_t cvtpk_bf16(float lo, float hi) {
  uint32_t r;
  asm("v_cvt_pk_bf16_f32 %0, %1, %2" : "=v"(r) : "v"(lo), "v"(hi));
  return r;
}

__device__ __forceinline__ f32x16 zero16() {
  f32x16 z;
#pragma unroll
  for (int i = 0; i < 16; ++i) z[i] = 0.f;
  return z;
}

// ---------------- prepass: fp32 -> bf16 elementwise (both inputs, one launch) --
__global__ __launch_bounds__(256) void cvt2_kernel(
    const float* __restrict__ s0, const float* __restrict__ s1,
    unsigned short* __restrict__ d0, unsigned short* __restrict__ d1, int n4) {
  const float* src = blockIdx.y ? s1 : s0;
  unsigned short* dst = blockIdx.y ? d1 : d0;
  int idx = blockIdx.x * 256 + threadIdx.x;
  int stride = gridDim.x * 256;
  for (int i = idx; i < n4; i += stride) {
    float4 f = ((const float4*)src)[i];
    us4 o = { f2bf(f.x), f2bf(f.y), f2bf(f.z), f2bf(f.w) };
    ((us4*)dst)[i] = o;
  }
}

// ---------------- prepass: fp32 [K][N] -> bf16 transposed [N][K] ----------------
__global__ __launch_bounds__(256) void tpose_kernel(
    const float* __restrict__ W0, const float* __restrict__ W1,
    const float* __restrict__ W2, const float* __restrict__ W3,
    unsigned short* __restrict__ T0, unsigned short* __restrict__ T1,
    unsigned short* __restrict__ T2, unsigned short* __restrict__ T3) {
  __shared__ float tile[32][33];
  const float* src; unsigned short* dst;
  switch (blockIdx.z) {
    case 0: src = W0; dst = T0; break;
    case 1: src = W1; dst = T1; break;
    case 2: src = W2; dst = T2; break;
    default: src = W3; dst = T3; break;
  }
  int x = threadIdx.x & 31, ys = threadIdx.x >> 5;
  int bx = blockIdx.x * 32, by = blockIdx.y * 32;
  for (int i = 0; i < 4; ++i) {
    int y = ys * 4 + i;
    tile[y][x] = src[(size_t)(by + y) * Dm + bx + x];
  }
  __syncthreads();
  for (int i = 0; i < 4; ++i) {
    int y = ys * 4 + i;
    dst[(size_t)(bx + y) * Dm + by + x] = f2bf(tile[x][y]);
  }
}

// ---------------- bf16 MFMA GEMM (unchanged from round 12) ----------------
__global__ __launch_bounds__(512) void gemm_kernel(
    const unsigned short* __restrict__ A0, const unsigned short* __restrict__ A1,
    const unsigned short* __restrict__ W0, const unsigned short* __restrict__ W1,
    const unsigned short* __restrict__ W2,
    const float* __restrict__ b0, const float* __restrict__ b1,
    const float* __restrict__ b2, const float* __restrict__ mask,
    unsigned short* __restrict__ Qw, unsigned short* __restrict__ Kw,
    unsigned short* __restrict__ Vtw, float* __restrict__ Of, int modeBase) {
  const int mode = modeBase + blockIdx.z;
  const unsigned short* Ap = (mode == 1 || mode == 2) ? A1 : A0;
  const unsigned short* Wp = (mode == 1) ? W1 : ((mode == 2) ? W2 : W0);
  const float* bias = (mode == 1) ? b1 : ((mode == 2) ? b2 : b0);

  const int tid = threadIdx.x, lane = tid & 63, wid = tid >> 6;  // 8 waves
  const int wm = wid >> 1, wn = wid & 1;
  const int m0 = blockIdx.x * 128, n0 = blockIdx.y * 128;
  const int ln = lane & 15, kg = lane >> 4;

  __shared__ __align__(16) unsigned short smem[24576];

  f32x4 acc[2][4];
#pragma unroll
  for (int i = 0; i < 2; ++i)
#pragma unroll
    for (int j = 0; j < 4; ++j) acc[i][j] = f32x4{0.f, 0.f, 0.f, 0.f};

  const int srow = tid >> 2;
  const int schx = (tid & 3) ^ ((srow >> 1) & 3);
  auto stage_g = [&](int buf, int k0) {
    __builtin_amdgcn_global_load_lds(
        (const AS1 unsigned int*)(Ap + (size_t)(m0 + srow) * Dm + k0 + schx * 8),
        (AS3 unsigned int*)&smem[buf * 4096 + wid * 512], 16, 0, 0);
    __builtin_amdgcn_global_load_lds(
        (const AS1 unsigned int*)(Wp + (size_t)(n0 + srow) * Dm + k0 + schx * 8),
        (AS3 unsigned int*)&smem[12288 + buf * 4096 + wid * 512], 16, 0, 0);
  };
  auto comp_g = [&](int buf) {
    const unsigned short* As = &smem[buf * 4096];
    const unsigned short* Bs = &smem[12288 + buf * 4096];
    const int rsw = kg ^ ((ln >> 1) & 3);
    bf16x8 af[2], bfv[4];
#pragma unroll
    for (int f = 0; f < 2; ++f)
      af[f] = *(const bf16x8*)&As[(wm * 32 + f * 16 + ln) * 32 + rsw * 8];
#pragma unroll
    for (int f = 0; f < 4; ++f)
      bfv[f] = *(const bf16x8*)&Bs[(wn * 64 + f * 16 + ln) * 32 + rsw * 8];
    __builtin_amdgcn_s_setprio(1);
#pragma unroll
    for (int mf = 0; mf < 2; ++mf)
#pragma unroll
      for (int nf = 0; nf < 4; ++nf)
        acc[mf][nf] = __builtin_amdgcn_mfma_f32_16x16x32_bf16(af[mf], bfv[nf],
                                                              acc[mf][nf], 0, 0, 0);
    __builtin_amdgcn_s_setprio(0);
  };

  stage_g(0, 0);
  stage_g(1, 32);
  for (int tt = 0; tt < 30; tt += 3) {
#pragma unroll
    for (int j = 0; j < 3; ++j) {
      const int t = tt + j;
      asm volatile("s_waitcnt vmcnt(2)" ::: "memory");
      asm volatile("s_barrier" ::: "memory");
      if (t < 30) stage_g((j + 2) % 3, (t + 2) * 32);
      comp_g(j);
    }
  }
  asm volatile("s_waitcnt vmcnt(2)" ::: "memory");
  asm volatile("s_barrier" ::: "memory");
  comp_g(0);                                   // t=30
  asm volatile("s_waitcnt vmcnt(0)" ::: "memory");
  asm volatile("s_barrier" ::: "memory");
  comp_g(1);                                   // t=31

  __syncthreads();
  unsigned short* ep = smem + wid * 2560;
  const int rowbase = m0 + wm * 32;
  const int colbase = n0 + wn * 64;

  if (mode <= 1) {
    unsigned short* dstbase = (mode == 0) ? Qw : Kw;
    const int hh = colbase >> 6;
    const int bb_ = rowbase >> 11, lb = rowbase & 2047;
    unsigned short* dst = dstbase + ((size_t)(bb_ * NH + hh) * Lq + lb) * DH;
    const float sc = (mode == 0) ? 0.18033688f : 1.0f;  // 0.125*log2(e)
    for (int nf = 0; nf < 4; ++nf) {
      const float bv_ = bias[colbase + nf * 16 + ln];
      for (int mf = 0; mf < 2; ++mf)
        for (int r = 0; r < 4; ++r)
          ep[(mf * 16 + kg * 4 + r) * 72 + nf * 16 + ln] =
              f2bf((acc[mf][nf][r] + bv_) * sc);
    }
    for (int it = 0; it < 4; ++it) {
      const int e = it * 64 + lane;
      const int rr = e >> 3, c = (e & 7) * 8;
      *(bf16x8*)(dst + (size_t)rr * DH + c) = *(const bf16x8*)&ep[rr * 72 + c];
    }
  } else if (mode == 2) {
    const int hh = colbase >> 6;
    const int bb_ = rowbase >> 11;
    const int l0 = rowbase & 2047;
    unsigned short* dst = Vtw + (size_t)(bb_ * NH + hh) * DH * Lq;
    for (int nf = 0; nf < 4; ++nf) {
      const int dh2 = nf * 16 + ln;
      const float bv_ = bias[colbase + dh2];
      for (int mf = 0; mf < 2; ++mf)
        for (int r = 0; r < 4; ++r) {
          const int rl = mf * 16 + kg * 4 + r;
          ep[dh2 * 40 + rl] = f2bf((acc[mf][nf][r] + bv_) * mask[rowbase + rl]);
        }
    }
    for (int it = 0; it < 4; ++it) {
      const int e = it * 64 + lane;
      const int dr = e >> 2, c = (e & 3) * 8;
      *(bf16x8*)(dst + (size_t)dr * Lq + l0 + c) = *(const bf16x8*)&ep[dr * 40 + c];
    }
  } else {
    float* epf = (float*)smem + wid * 1280;
    for (int mf = 0; mf < 2; ++mf) {
      for (int nf = 0; nf < 4; ++nf) {
        const float bv_ = bias[colbase + nf * 16 + ln];
        for (int r = 0; r < 4; ++r)
          epf[(kg * 4 + r) * 68 + nf * 16 + ln] = acc[mf][nf][r] + bv_;
      }
      for (int it = 0; it < 4; ++it) {
        const int e = it * 64 + lane;
        const int rr = e >> 4, c = (lane & 15) * 4;
        *(f32x4*)(Of + (size_t)(rowbase + mf * 16 + rr) * Dm + colbase + c) =
            *(const f32x4*)&epf[rr * 68 + c];
      }
    }
  }
}

// ---------------- flash attention, round 13: 16 waves, 4-way KV split --------
// 1024 threads: 4 q-waves (wq, 32 q-rows each) x 4 key-quarters (qu, 512 keys
// each, 16 tiles). Grid 512 -> 2 blocks/CU x 16 waves = 32 waves/CU = 8/SIMD
// (HW max; R12 was 4/SIMD and chain-latency-bound).
// LDS 64 KB: per quarter 2 K bufs + 2 V bufs (2-buffer forces the schedule:
//   vmcnt(2) -> barrier -> compute(t) -> lgkmcnt(0) -> barrier -> stage(t+2)
// The lgkmcnt(0) is REQUIRED: stage overwrites the buffer this iteration's
// ds_reads used; reads must drain before any wave passes barrier2 (WAR).
// Combine: 3 sequential LDS rounds (quarter r writes f32 O/l partials,
// quarter 0 adds); pure add thanks to no-max exp2 softmax.
// T1: XCD-swizzled block decode -> each XCD owns 4 (b,h) groups x 16 q-tiles;
// K/V working set 2 MB <= 4 MB L2 -> HBM fetch ~once.
__global__ __launch_bounds__(1024) void attn_kernel(
    const unsigned short* __restrict__ Q, const unsigned short* __restrict__ K,
    const unsigned short* __restrict__ Vt, unsigned short* __restrict__ X) {
  const int tid = threadIdx.x, lane = tid & 63, wv = tid >> 6;  // 16 waves
  const int lq = lane & 31, hi = lane >> 5;
  const int wq = wv & 3, qu = wv >> 2;
  // XCD-aware decode of 512 blocks: xcd = bid&7 owns groups g = xcd*4..+3
  const int bid = blockIdx.x;
  const int slot = bid >> 3;
  const int g = (bid & 7) * 4 + (slot >> 4);   // (h,b) group 0..31
  const int qt = slot & 15;
  const int h = g & 15, b = g >> 4;
  const int q0 = qt * 128 + wq * 32;

  const size_t bh = (size_t)b * NH + h;
  const unsigned short* Qp = Q + bh * Lq * DH;
  const unsigned short* Kp = K + bh * Lq * DH + (size_t)qu * 512 * DH;
  const unsigned short* Vp = Vt + bh * DH * Lq + qu * 512;

  // 64 KB: quarter qu owns smem[qu*8192 .. +8192) shorts:
  //   K bufs [0,2048),[2048,4096); V bufs [4096,6144),[6144,8192)
  __shared__ __align__(16) unsigned short smem[32768];
  unsigned short* Klds = smem + qu * 8192;
  unsigned short* Vlds = smem + qu * 8192 + 4096;

  // staging sources (inverse-swizzled): each thread 1 K-chunk + 1 V-chunk of
  // its own quarter (st = thread index within the quarter's 256 threads)
  const int st = tid & 255;
  const int kr = st >> 3, kc = st & 7;
  const unsigned short* ksrc = Kp + (size_t)kr * DH + ((kc ^ (kr & 7)) * 8);
  const int vr = st >> 2, vc = st & 3;
  const unsigned short* vsrc = Vp + (size_t)vr * Lq + ((vc ^ ((vr >> 1) & 3)) * 8);

  auto stage = [&](int buf, const unsigned short* kp, const unsigned short* vp) {
    __builtin_amdgcn_global_load_lds((const AS1 unsigned int*)kp,
        (AS3 unsigned int*)&Klds[buf * 2048 + wq * 512], 16, 0, 0);
    __builtin_amdgcn_global_load_lds((const AS1 unsigned int*)vp,
        (AS3 unsigned int*)&Vlds[buf * 2048 + wq * 512], 16, 0, 0);
  };

  bf16x8 qf[4];
#pragma unroll
  for (int ks = 0; ks < 4; ++ks)
    qf[ks] = *(const bf16x8*)(Qp + (size_t)(q0 + lq) * DH + ks * 16 + hi * 8);

  bf16x8 onesf;
#pragma unroll
  for (int i = 0; i < 8; ++i) onesf[i] = (short)0x3F80;   // bf16 1.0

  f32x16 o0 = zero16(), o1 = zero16(), lacc = zero16();

  auto compute = [&](int buf) {
    const unsigned short* Kb = &Klds[buf * 2048];
    const unsigned short* Vb = &Vlds[buf * 2048];
    // QK^T: single chained accumulator (k = 4 x 16)
    f32x16 s = zero16();
    __builtin_amdgcn_s_setprio(1);
#pragma unroll
    for (int ks = 0; ks < 4; ++ks) {
      const bf16x8 kfr =
          *(const bf16x8*)&Kb[lq * 64 + (((2 * ks + hi) ^ (lq & 7)) * 8)];
      s = __builtin_amdgcn_mfma_f32_32x32x16_bf16(kfr, qf[ks], s, 0, 0, 0);
    }
    __builtin_amdgcn_s_setprio(0);

    // softmax (exp2 domain, no max subtraction)
    float p[16];
#pragma unroll
    for (int i = 0; i < 16; ++i) p[i] = exp2_fast(s[i]);

    // T12: pack + half-wave exchange -> PV A-frags
    uint32_t a00 = cvtpk_bf16(p[0],  p[1]),  a01 = cvtpk_bf16(p[2],  p[3]);
    uint32_t a10 = cvtpk_bf16(p[4],  p[5]),  a11 = cvtpk_bf16(p[6],  p[7]);
    uint32_t a20 = cvtpk_bf16(p[8],  p[9]),  a21 = cvtpk_bf16(p[10], p[11]);
    uint32_t a30 = cvtpk_bf16(p[12], p[13]), a31 = cvtpk_bf16(p[14], p[15]);
    asm volatile("v_permlane32_swap_b32 %0, %1" : "+v"(a00), "+v"(a10));
    asm volatile("v_permlane32_swap_b32 %0, %1" : "+v"(a01), "+v"(a11));
    asm volatile("v_permlane32_swap_b32 %0, %1" : "+v"(a20), "+v"(a30));
    asm volatile("v_permlane32_swap_b32 %0, %1" : "+v"(a21), "+v"(a31));
    u32x4 pw0 = {a00, a01, a10, a11};
    u32x4 pw1 = {a20, a21, a30, a31};
    const bf16x8 pa0 = *(const bf16x8*)&pw0;
    const bf16x8 pa1 = *(const bf16x8*)&pw1;

    // PV + l-accumulation on the matrix pipe
    __builtin_amdgcn_s_setprio(1);
    lacc = __builtin_amdgcn_mfma_f32_32x32x16_bf16(pa0, onesf, lacc, 0, 0, 0);
    lacc = __builtin_amdgcn_mfma_f32_32x32x16_bf16(pa1, onesf, lacc, 0, 0, 0);
    {
      const int sw0 = (lq >> 1) & 3;                     // dh = lq
      const bf16x8 vb0 = *(const bf16x8*)&Vb[lq * 32 + ((hi ^ sw0) * 8)];
      const bf16x8 vb1 = *(const bf16x8*)&Vb[lq * 32 + (((2 + hi) ^ sw0) * 8)];
      o0 = __builtin_amdgcn_mfma_f32_32x32x16_bf16(pa0, vb0, o0, 0, 0, 0);
      o0 = __builtin_amdgcn_mfma_f32_32x32x16_bf16(pa1, vb1, o0, 0, 0, 0);
      const int dh1 = 32 + lq;
      const int sw1 = (dh1 >> 1) & 3;
      const bf16x8 vb2 = *(const bf16x8*)&Vb[dh1 * 32 + ((hi ^ sw1) * 8)];
      const bf16x8 vb3 = *(const bf16x8*)&Vb[dh1 * 32 + (((2 + hi) ^ sw1) * 8)];
      o1 = __builtin_amdgcn_mfma_f32_32x32x16_bf16(pa0, vb2, o1, 0, 0, 0);
      o1 = __builtin_amdgcn_mfma_f32_32x32x16_bf16(pa1, vb3, o1, 0, 0, 0);
    }
    __builtin_amdgcn_s_setprio(0);
  };

  // prologue: stage tiles 0,1 (4 loads in flight per thread)
  stage(0, ksrc, vsrc);
  stage(1, ksrc + 2048, vsrc + 32);   // per tile: K +32*DH elems, V +32 elems
  const unsigned short* kpre = ksrc + 4096;
  const unsigned short* vpre = vsrc + 64;
#pragma unroll 2
  for (int t = 0; t < 14; ++t) {      // tiles 0..13; buffer = t&1
    asm volatile("s_waitcnt vmcnt(2)" ::: "memory");   // tile t landed (mine)
    asm volatile("s_barrier" ::: "memory");            // tile t landed (all)
    compute(t & 1);
    asm volatile("s_waitcnt lgkmcnt(0)" ::: "memory"); // my ds_reads drained
    asm volatile("s_barrier" ::: "memory");            // all waves' reads done
    stage(t & 1, kpre, vpre);                          // overwrite same buf: safe
    kpre += 2048; vpre += 32;
  }
  asm volatile("s_waitcnt vmcnt(2)" ::: "memory");     // tile 14 landed
  asm volatile("s_barrier" ::: "memory");
  compute(0);                                          // t=14
  asm volatile("s_waitcnt vmcnt(0)" ::: "memory");     // tile 15 landed
  asm volatile("s_barrier" ::: "memory");
  compute(1);                                          // t=15

  // ---- combine quarters (pure add), 3 sequential rounds ----
  __syncthreads();
  float* cs = (float*)smem;
  float* po = cs + wq * 2048;           // [32 q][64 dh] f32 per q-wave (8 KB)
  float* pl = cs + 8192 + wq * 32;      // l partials per q-wave
#pragma unroll
  for (int rr = 1; rr < 4; ++rr) {
    if (qu == rr) {
#pragma unroll
      for (int r = 0; r < 16; ++r) {
        const int qrow = (r & 3) + 8 * (r >> 2) + 4 * hi;
        po[qrow * 64 + lq]      = o0[r];
        po[qrow * 64 + 32 + lq] = o1[r];
      }
      if (lq == 0) {
#pragma unroll
        for (int r = 0; r < 16; ++r)
          pl[(r & 3) + 8 * (r >> 2) + 4 * hi] = lacc[r];
      }
    }
    __syncthreads();
    if (qu == 0) {
#pragma unroll
      for (int r = 0; r < 16; ++r) {
        const int qrow = (r & 3) + 8 * (r >> 2) + 4 * hi;
        o0[r]   += po[qrow * 64 + lq];
        o1[r]   += po[qrow * 64 + 32 + lq];
        lacc[r] += pl[qrow];
      }
    }
    __syncthreads();   // reader done before next round's writer clobbers po
  }

  if (qu == 0) {
    // normalize + LDS-stage + 16B coalesced store (reuses this q-wave's po)
    unsigned short* ep = (unsigned short*)po;   // [32][72] bf16 (4608B < 8KB)
#pragma unroll
    for (int r = 0; r < 16; ++r) {
      const int qrow = (r & 3) + 8 * (r >> 2) + 4 * hi;
      const float iv = 1.0f / lacc[r];
      ep[qrow * 72 + lq]      = f2bf(o0[r] * iv);
      ep[qrow * 72 + 32 + lq] = f2bf(o1[r] * iv);
    }
#pragma unroll
    for (int it = 0; it < 4; ++it) {    // same-wave DS order: no barrier needed
      const int e = it * 64 + lane;
      const int row = e >> 3, ch = e & 7;
      *(bf16x8*)(X + (size_t)(b * Lq + q0 + row) * Dm + h * DH + ch * 8) =
          *(const bf16x8*)&ep[row * 72 + ch * 8];
    }
  }
}

// ---------------- launch ----------------
extern "C" void kernel_launch(void* const* d_in, const int* in_sizes, int n_in,
                              void* d_out, int out_size, void* d_ws, size_t ws_size,
                              hipStream_t stream) {
  (void)in_sizes; (void)n_in; (void)out_size; (void)ws_size;
  const float* inputs_q  = (const float*)d_in[0];
  const float* inputs_kv = (const float*)d_in[1];
  const float* mask_k    = (const float*)d_in[2];
  const float* Wq = (const float*)d_in[3];
  const float* bq = (const float*)d_in[4];
  const float* Wk = (const float*)d_in[5];
  const float* bk = (const float*)d_in[6];
  const float* Wv = (const float*)d_in[7];
  const float* bv = (const float*)d_in[8];
  const float* Wo = (const float*)d_in[9];
  const float* bo = (const float*)d_in[10];
  float* out = (float*)d_out;

  unsigned short* ws = (unsigned short*)d_ws;
  const size_t BIG = 4194304;   // 4096*1024 elems
  const size_t WSZ = 1048576;   // 1024*1024 elems
  unsigned short* Xq  = ws;             // activations bf16
  unsigned short* Xkv = Xq + BIG;
  unsigned short* Wqt = Xkv + BIG;      // transposed weights bf16
  unsigned short* Wkt = Wqt + WSZ;
  unsigned short* Wvt = Wkt + WSZ;
  unsigned short* Wot = Wvt + WSZ;
  unsigned short* Qw  = Wot + WSZ;      // [B,H,L,Dh] (exp2-domain scale)
  unsigned short* Kw  = Qw + BIG;       // [B,H,L,Dh]
  unsigned short* Vtw = Kw + BIG;       // [B,H,Dh,L]
  unsigned short* Xat = Vtw + BIG;      // attention out [B*L, H*Dh]

  cvt2_kernel<<<dim3(512, 2), 256, 0, stream>>>(inputs_q, inputs_kv, Xq, Xkv,
                                                (int)(BIG / 4));
  tpose_kernel<<<dim3(32, 32, 4), 256, 0, stream>>>(Wq, Wk, Wv, Wo, Wqt, Wkt, Wvt, Wot);
  gemm_kernel<<<dim3(32, 8, 3), 512, 0, stream>>>(Xq, Xkv, Wqt, Wkt, Wvt, bq, bk, bv,
                                                  mask_k, Qw, Kw, Vtw, nullptr, 0);
  attn_kernel<<<dim3(512, 1, 1), 1024, 0, stream>>>(Qw, Kw, Vtw, Xat);
  gemm_kernel<<<dim3(32, 8, 1), 512, 0, stream>>>(Xat, nullptr, Wot, nullptr, nullptr,
                                                  bo, nullptr, nullptr, nullptr,
                                                  nullptr, nullptr, nullptr, out, 3);
}